// Round 1
// baseline (506.217 us; speedup 1.0000x reference)
//
#include <hip/hip_runtime.h>
#include <hip/hip_bf16.h>

// ce[n] = 0.5 * (LSE(x[n,:]) + LSE(y[n,:]) - max_c(x[n,c]+y[n,c]))
// out   = mean_n ce[n]
//
// One 256-thread block per row (C=2048): each thread loads 2 float4 from x
// and 2 float4 from y (8 elems each), keeps them in registers, computes the
// three row maxes, then the two exp-sums from the same registers.

#define ROW_C 2048
#define BLK   256

__device__ __forceinline__ float wave_max(float v) {
#pragma unroll
    for (int off = 32; off; off >>= 1) v = fmaxf(v, __shfl_xor(v, off));
    return v;
}
__device__ __forceinline__ float wave_sum(float v) {
#pragma unroll
    for (int off = 32; off; off >>= 1) v += __shfl_xor(v, off);
    return v;
}

__global__ __launch_bounds__(BLK) void mecl_row_kernel(
        const float* __restrict__ x, const float* __restrict__ y,
        float* __restrict__ ce) {
    const int row = blockIdx.x;
    const int t = threadIdx.x;
    const size_t base = (size_t)row * ROW_C;

    const float4* xr = reinterpret_cast<const float4*>(x + base);
    const float4* yr = reinterpret_cast<const float4*>(y + base);

    // 2 passes of 256 lanes * 4 floats = 2048 floats per matrix
    float4 x0 = xr[t];
    float4 x1 = xr[t + BLK];
    float4 y0 = yr[t];
    float4 y1 = yr[t + BLK];

    float mx = fmaxf(fmaxf(fmaxf(x0.x, x0.y), fmaxf(x0.z, x0.w)),
                     fmaxf(fmaxf(x1.x, x1.y), fmaxf(x1.z, x1.w)));
    float my = fmaxf(fmaxf(fmaxf(y0.x, y0.y), fmaxf(y0.z, y0.w)),
                     fmaxf(fmaxf(y1.x, y1.y), fmaxf(y1.z, y1.w)));

    float s0 = x0.x + y0.x, s1 = x0.y + y0.y, s2 = x0.z + y0.z, s3 = x0.w + y0.w;
    float s4 = x1.x + y1.x, s5 = x1.y + y1.y, s6 = x1.z + y1.z, s7 = x1.w + y1.w;
    float mxy = fmaxf(fmaxf(fmaxf(s0, s1), fmaxf(s2, s3)),
                      fmaxf(fmaxf(s4, s5), fmaxf(s6, s7)));

    mx  = wave_max(mx);
    my  = wave_max(my);
    mxy = wave_max(mxy);

    __shared__ float smx[4], smy[4], smxy[4];
    const int wave = t >> 6;
    if ((t & 63) == 0) { smx[wave] = mx; smy[wave] = my; smxy[wave] = mxy; }
    __syncthreads();
    mx  = fmaxf(fmaxf(smx[0],  smx[1]),  fmaxf(smx[2],  smx[3]));
    my  = fmaxf(fmaxf(smy[0],  smy[1]),  fmaxf(smy[2],  smy[3]));
    mxy = fmaxf(fmaxf(smxy[0], smxy[1]), fmaxf(smxy[2], smxy[3]));

    float sx = __expf(x0.x - mx) + __expf(x0.y - mx) + __expf(x0.z - mx) + __expf(x0.w - mx)
             + __expf(x1.x - mx) + __expf(x1.y - mx) + __expf(x1.z - mx) + __expf(x1.w - mx);
    float sy = __expf(y0.x - my) + __expf(y0.y - my) + __expf(y0.z - my) + __expf(y0.w - my)
             + __expf(y1.x - my) + __expf(y1.y - my) + __expf(y1.z - my) + __expf(y1.w - my);

    sx = wave_sum(sx);
    sy = wave_sum(sy);

    __shared__ float ssx[4], ssy[4];
    if ((t & 63) == 0) { ssx[wave] = sx; ssy[wave] = sy; }
    __syncthreads();
    if (t == 0) {
        sx = ssx[0] + ssx[1] + ssx[2] + ssx[3];
        sy = ssy[0] + ssy[1] + ssy[2] + ssy[3];
        float lse_x = mx + __logf(sx);
        float lse_y = my + __logf(sy);
        ce[row] = 0.5f * (lse_x + lse_y - mxy);
    }
}

// Atomic fallback if ws is too small: adds ce[row]/N directly to out[0].
__global__ __launch_bounds__(BLK) void mecl_row_atomic_kernel(
        const float* __restrict__ x, const float* __restrict__ y,
        float* __restrict__ out, float inv_n) {
    const int row = blockIdx.x;
    const int t = threadIdx.x;
    const size_t base = (size_t)row * ROW_C;
    const float4* xr = reinterpret_cast<const float4*>(x + base);
    const float4* yr = reinterpret_cast<const float4*>(y + base);
    float4 x0 = xr[t], x1 = xr[t + BLK];
    float4 y0 = yr[t], y1 = yr[t + BLK];

    float mx = fmaxf(fmaxf(fmaxf(x0.x, x0.y), fmaxf(x0.z, x0.w)),
                     fmaxf(fmaxf(x1.x, x1.y), fmaxf(x1.z, x1.w)));
    float my = fmaxf(fmaxf(fmaxf(y0.x, y0.y), fmaxf(y0.z, y0.w)),
                     fmaxf(fmaxf(y1.x, y1.y), fmaxf(y1.z, y1.w)));
    float s0 = x0.x + y0.x, s1 = x0.y + y0.y, s2 = x0.z + y0.z, s3 = x0.w + y0.w;
    float s4 = x1.x + y1.x, s5 = x1.y + y1.y, s6 = x1.z + y1.z, s7 = x1.w + y1.w;
    float mxy = fmaxf(fmaxf(fmaxf(s0, s1), fmaxf(s2, s3)),
                      fmaxf(fmaxf(s4, s5), fmaxf(s6, s7)));
    mx = wave_max(mx); my = wave_max(my); mxy = wave_max(mxy);
    __shared__ float smx[4], smy[4], smxy[4];
    const int wave = t >> 6;
    if ((t & 63) == 0) { smx[wave] = mx; smy[wave] = my; smxy[wave] = mxy; }
    __syncthreads();
    mx  = fmaxf(fmaxf(smx[0],  smx[1]),  fmaxf(smx[2],  smx[3]));
    my  = fmaxf(fmaxf(smy[0],  smy[1]),  fmaxf(smy[2],  smy[3]));
    mxy = fmaxf(fmaxf(smxy[0], smxy[1]), fmaxf(smxy[2], smxy[3]));
    float sx = __expf(x0.x - mx) + __expf(x0.y - mx) + __expf(x0.z - mx) + __expf(x0.w - mx)
             + __expf(x1.x - mx) + __expf(x1.y - mx) + __expf(x1.z - mx) + __expf(x1.w - mx);
    float sy = __expf(y0.x - my) + __expf(y0.y - my) + __expf(y0.z - my) + __expf(y0.w - my)
             + __expf(y1.x - my) + __expf(y1.y - my) + __expf(y1.z - my) + __expf(y1.w - my);
    sx = wave_sum(sx); sy = wave_sum(sy);
    __shared__ float ssx[4], ssy[4];
    if ((t & 63) == 0) { ssx[wave] = sx; ssy[wave] = sy; }
    __syncthreads();
    if (t == 0) {
        sx = ssx[0] + ssx[1] + ssx[2] + ssx[3];
        sy = ssy[0] + ssy[1] + ssy[2] + ssy[3];
        float ce = 0.5f * ((mx + __logf(sx)) + (my + __logf(sy)) - mxy);
        atomicAdd(out, ce * inv_n);
    }
}

__global__ __launch_bounds__(1024) void mecl_reduce_kernel(
        const float* __restrict__ ws, float* __restrict__ out,
        int n, float inv_n) {
    float s = 0.0f;
    for (int i = threadIdx.x; i < n; i += 1024) s += ws[i];
    s = wave_sum(s);
    __shared__ float sb[16];
    const int wave = threadIdx.x >> 6;
    if ((threadIdx.x & 63) == 0) sb[wave] = s;
    __syncthreads();
    if (threadIdx.x == 0) {
        float tot = 0.0f;
#pragma unroll
        for (int w = 0; w < 16; ++w) tot += sb[w];
        out[0] = tot * inv_n;
    }
}

extern "C" void kernel_launch(void* const* d_in, const int* in_sizes, int n_in,
                              void* d_out, int out_size, void* d_ws, size_t ws_size,
                              hipStream_t stream) {
    const float* x = (const float*)d_in[0];
    const float* y = (const float*)d_in[1];
    float* out = (float*)d_out;

    const int total = in_sizes[0];
    const int N = total / ROW_C;   // 32768
    const float inv_n = 1.0f / (float)N;

    if (ws_size >= (size_t)N * sizeof(float)) {
        float* ws = (float*)d_ws;
        mecl_row_kernel<<<N, BLK, 0, stream>>>(x, y, ws);
        mecl_reduce_kernel<<<1, 1024, 0, stream>>>(ws, out, N, inv_n);
    } else {
        hipMemsetAsync(d_out, 0, sizeof(float), stream);
        mecl_row_atomic_kernel<<<N, BLK, 0, stream>>>(x, y, out, inv_n);
    }
}